// Round 2
// baseline (1662.116 us; speedup 1.0000x reference)
//
#include <hip/hip_runtime.h>
#include <math.h>

#define N_NODES 100000
#define N_EDGES 3200000
#define DIM 256

typedef unsigned short u16;
typedef unsigned int u32;
typedef __attribute__((ext_vector_type(8))) short bf16x8;
typedef __attribute__((ext_vector_type(4))) float f32x4;

__device__ __forceinline__ float bf2f(u16 u) {
    union { u32 i; float f; } v; v.i = ((u32)u) << 16; return v.f;
}
__device__ __forceinline__ u16 f2bf(float f) {
    union { float f; u32 i; } v; v.f = f;
    u32 x = v.i;
    return (u16)((x + 0x7fffu + ((x >> 16) & 1u)) >> 16);
}
// bit-level inf/nan -> 0 (immune to fast-math)
__device__ __forceinline__ float sane(float v) {
    union { float f; u32 i; } u; u.f = v;
    if ((u.i & 0x7f800000u) == 0x7f800000u) return 0.f;
    return v;
}
__device__ __forceinline__ int iclamp(int v, int lo, int hi) {
    return v < lo ? lo : (v > hi ? hi : v);
}

// ---- runtime format probes ---------------------------------------------
// flags[0]: 1 => float tensors are fp32, 0 => bf16
// flags[1]: 1 => edge_index is int64 (little-endian lo/hi word pairs), 0 => int32
__global__ void detect_kernel(const u32* __restrict__ xw_words,
                              const int* __restrict__ ei, int* __restrict__ flags) {
    if (blockIdx.x != 0 || threadIdx.x != 0) return;
    int cnt = 0;
    for (int j = 0; j < 256; ++j) {
        u32 e = (xw_words[j] >> 7) & 0xffu;  // bf16-pair: low-half exponent field
        cnt += (e >= 0x70 && e <= 0x88) ? 1 : 0;
    }
    flags[0] = (cnt < 128) ? 1 : 0;
    int allz = 1;
    for (int j = 1; j < 512; j += 2) allz &= (ei[j] == 0) ? 1 : 0;
    flags[1] = allz;
}

__device__ __forceinline__ int edge_val(const int* __restrict__ ei, int which,
                                        int i, int f64) {
    long long idx = (long long)which * N_EDGES + i;
    int v = f64 ? ei[idx * 2] : ei[idx];
    return iclamp(v, 0, N_NODES - 1);
}

// ---- canonicalize x to internal bf16 -----------------------------------
__global__ void convert_x(const void* __restrict__ xin, u16* __restrict__ xbf,
                          const int* __restrict__ flags) {
    long long i = (long long)blockIdx.x * blockDim.x + threadIdx.x;
    if (i >= (long long)N_NODES * DIM) return;
    float v = flags[0] ? ((const float*)xin)[i] : bf2f(((const u16*)xin)[i]);
    xbf[i] = f2bf(sane(v));
}

// ---- CSR build ---------------------------------------------------------
__global__ void count_deg(const int* __restrict__ ei, int* __restrict__ rowcount,
                          const int* __restrict__ flags) {
    int i = blockIdx.x * blockDim.x + threadIdx.x;
    if (i < N_EDGES) {
        int d = edge_val(ei, 1, i, flags[1]);
        atomicAdd(&rowcount[d], 1);
    }
}

__global__ void compute_dis(const int* __restrict__ rowcount, float* __restrict__ dis) {
    int i = blockIdx.x * blockDim.x + threadIdx.x;
    if (i < N_NODES) {
        int c = iclamp(rowcount[i], 0, N_EDGES);
        dis[i] = rsqrtf((float)(c + 1));  // +1 self loop; arg >= 1, no NaN
    }
}

// single-block hierarchical exclusive scan
__global__ void scan_kernel(const int* __restrict__ cnt, int* __restrict__ rowptr,
                            int* __restrict__ cursor) {
    __shared__ int wsum[16];
    __shared__ int s_carry;
    int lane = threadIdx.x & 63;
    int wid = threadIdx.x >> 6;
    if (threadIdx.x == 0) s_carry = 0;
    __syncthreads();
    for (int base = 0; base < N_NODES; base += 1024) {
        int i = base + (int)threadIdx.x;
        int c = (i < N_NODES) ? cnt[i] : 0;
        int v = c;
#pragma unroll
        for (int off = 1; off < 64; off <<= 1) {
            int t = __shfl_up(v, off, 64);
            if (lane >= off) v += t;
        }
        if (lane == 63) wsum[wid] = v;
        __syncthreads();
        int carry = s_carry;
        int woff = 0;
        for (int w = 0; w < wid; ++w) woff += wsum[w];
        int excl = carry + woff + v - c;
        if (i < N_NODES) { rowptr[i] = excl; cursor[i] = excl; }
        __syncthreads();
        if (threadIdx.x == 0) {
            int tot = 0;
            for (int w = 0; w < 16; ++w) tot += wsum[w];
            s_carry = carry + tot;
        }
        __syncthreads();
    }
    if (threadIdx.x == 0) rowptr[N_NODES] = s_carry;
}

__global__ void fill_csr(const int* __restrict__ ei, int* __restrict__ cursor,
                         int* __restrict__ colidx, const int* __restrict__ flags) {
    int i = blockIdx.x * blockDim.x + threadIdx.x;
    if (i < N_EDGES) {
        int f = flags[1];
        int s = edge_val(ei, 0, i, f);
        int d = edge_val(ei, 1, i, f);
        int pos = atomicAdd(&cursor[d], 1);
        pos = iclamp(pos, 0, N_EDGES - 1);
        colidx[pos] = s;
    }
}

// ---- weight transpose (dtype-aware) ------------------------------------
__global__ void transpose_w(const void* __restrict__ W, u16* __restrict__ Wt,
                            const int* __restrict__ flags) {
    int n = blockIdx.x;
    int k = threadIdx.x;
    float v = flags[0] ? ((const float*)W)[k * DIM + n]
                       : bf2f(((const u16*)W)[k * DIM + n]);
    Wt[n * DIM + k] = f2bf(sane(v));
}

// ---- dense GEMM: xw = A @ W via Wt, bf16 MFMA --------------------------
__global__ __launch_bounds__(256) void gemm_mfma(const u16* __restrict__ A,
                                                 const u16* __restrict__ Wt,
                                                 u16* __restrict__ out, int M) {
    int wid = threadIdx.x >> 6;
    int lane = threadIdx.x & 63;
    int rt = blockIdx.x * 4 + wid;
    if (rt * 16 >= M) return;
    int m = lane & 15;
    int quad = lane >> 4;
    const u16* arow = A + (size_t)(rt * 16 + m) * DIM + quad * 8;

    f32x4 acc[16];
#pragma unroll
    for (int t = 0; t < 16; ++t) acc[t] = (f32x4){0.f, 0.f, 0.f, 0.f};

#pragma unroll
    for (int ks = 0; ks < 8; ++ks) {
        bf16x8 a = *(const bf16x8*)(arow + ks * 32);
#pragma unroll
        for (int t = 0; t < 16; ++t) {
            bf16x8 b = *(const bf16x8*)(Wt + (size_t)(t * 16 + m) * DIM + ks * 32 + quad * 8);
            acc[t] = __builtin_amdgcn_mfma_f32_16x16x32_bf16(a, b, acc[t], 0, 0, 0);
        }
    }
#pragma unroll
    for (int t = 0; t < 16; ++t) {
#pragma unroll
        for (int r = 0; r < 4; ++r) {
            int row = rt * 16 + quad * 4 + r;
            int c = t * 16 + m;
            out[(size_t)row * DIM + c] = f2bf(sane(acc[t][r]));
        }
    }
}

// ---- aggregation + bias + ELU ------------------------------------------
// out[d] = elu(dis[d]*(sum_s dis[s]*xw[s] + dis[d]*xw[d]) + b)
// final==0: always store bf16 (hidden layer). final==1: store per flags[0].
__global__ __launch_bounds__(256) void aggregate(const u16* __restrict__ xw,
                                                 const int* __restrict__ rowptr,
                                                 const int* __restrict__ colidx,
                                                 const float* __restrict__ dis,
                                                 const void* __restrict__ bias,
                                                 void* __restrict__ out,
                                                 const int* __restrict__ flags,
                                                 int final_layer) {
    int wid = threadIdx.x >> 6;
    int lane = threadIdx.x & 63;
    int node = blockIdx.x * 4 + wid;
    if (node >= N_NODES) return;
    int c0 = lane * 4;
    int f32mode = flags[0];

    float dn = dis[node];
    float a0, a1, a2, a3;
    {
        ushort4 v = *(const ushort4*)(xw + (size_t)node * DIM + c0);
        a0 = dn * bf2f(v.x); a1 = dn * bf2f(v.y);
        a2 = dn * bf2f(v.z); a3 = dn * bf2f(v.w);
    }
    int beg = iclamp(rowptr[node], 0, N_EDGES);
    int end = iclamp(rowptr[node + 1], beg, N_EDGES);
    for (int e = beg; e < end; ++e) {
        int s = iclamp(colidx[e], 0, N_NODES - 1);
        float w = dis[s];
        ushort4 v = *(const ushort4*)(xw + (size_t)s * DIM + c0);
        a0 += w * bf2f(v.x); a1 += w * bf2f(v.y);
        a2 += w * bf2f(v.z); a3 += w * bf2f(v.w);
    }
    float b0, b1, b2, b3;
    if (f32mode) {
        float4 bv = *(const float4*)((const float*)bias + c0);
        b0 = bv.x; b1 = bv.y; b2 = bv.z; b3 = bv.w;
    } else {
        ushort4 bv = *(const ushort4*)((const u16*)bias + c0);
        b0 = bf2f(bv.x); b1 = bf2f(bv.y); b2 = bf2f(bv.z); b3 = bf2f(bv.w);
    }
    float o0 = dn * a0 + b0;
    float o1 = dn * a1 + b1;
    float o2 = dn * a2 + b2;
    float o3 = dn * a3 + b3;
    o0 = sane(o0 > 0.f ? o0 : expm1f(o0));
    o1 = sane(o1 > 0.f ? o1 : expm1f(o1));
    o2 = sane(o2 > 0.f ? o2 : expm1f(o2));
    o3 = sane(o3 > 0.f ? o3 : expm1f(o3));
    if (final_layer && f32mode) {
        float4 ov; ov.x = o0; ov.y = o1; ov.z = o2; ov.w = o3;
        *(float4*)((float*)out + (size_t)node * DIM + c0) = ov;
    } else {
        ushort4 ov;
        ov.x = f2bf(o0); ov.y = f2bf(o1); ov.z = f2bf(o2); ov.w = f2bf(o3);
        *(ushort4*)((u16*)out + (size_t)node * DIM + c0) = ov;
    }
}

// ---- launch ------------------------------------------------------------
extern "C" void kernel_launch(void* const* d_in, const int* in_sizes, int n_in,
                              void* d_out, int out_size, void* d_ws, size_t ws_size,
                              hipStream_t stream) {
    const void* x  = d_in[0];
    const int*  ei = (const int*)d_in[1];
    const void* W1 = d_in[2];
    const void* b1 = d_in[3];
    const void* W2 = d_in[4];
    const void* b2 = d_in[5];

    char* ws = (char*)d_ws;
    size_t off = 0;
    auto alloc = [&](size_t bytes) {
        void* p = ws + off;
        off = (off + bytes + 255) & ~(size_t)255;
        return p;
    };
    int*   flags    = (int*)alloc(256);
    int*   rowcount = (int*)alloc((size_t)N_NODES * 4);
    int*   rowptr   = (int*)alloc((size_t)(N_NODES + 1) * 4);
    int*   cursor   = (int*)alloc((size_t)N_NODES * 4);
    int*   colidx   = (int*)alloc((size_t)N_EDGES * 4);
    float* dis      = (float*)alloc((size_t)N_NODES * 4);
    u16*   Wt       = (u16*)alloc((size_t)DIM * DIM * 2);
    u16*   xw       = (u16*)alloc((size_t)N_NODES * DIM * 2);
    (void)ws_size;

    // d_out doubles as scratch for the canonical-bf16 x copy, then holds h.
    u16* xbf = (u16*)d_out;

    detect_kernel<<<1, 64, 0, stream>>>((const u32*)x, ei, flags);
    hipMemsetAsync(rowcount, 0, (size_t)N_NODES * 4, stream);
    convert_x<<<(N_NODES * DIM + 255) / 256, 256, 0, stream>>>(x, xbf, flags);
    count_deg<<<(N_EDGES + 255) / 256, 256, 0, stream>>>(ei, rowcount, flags);
    compute_dis<<<(N_NODES + 255) / 256, 256, 0, stream>>>(rowcount, dis);
    scan_kernel<<<1, 1024, 0, stream>>>(rowcount, rowptr, cursor);
    fill_csr<<<(N_EDGES + 255) / 256, 256, 0, stream>>>(ei, cursor, colidx, flags);

    int gemm_blocks = (N_NODES / 16 + 3) / 4;

    // layer 1: xw = xbf@W1 ; h (bf16, in d_out) = elu(agg + b1)
    transpose_w<<<DIM, DIM, 0, stream>>>(W1, Wt, flags);
    gemm_mfma<<<gemm_blocks, 256, 0, stream>>>(xbf, Wt, xw, N_NODES);
    aggregate<<<N_NODES / 4, 256, 0, stream>>>(xw, rowptr, colidx, dis, b1, d_out, flags, 0);

    // layer 2: xw = h@W2 ; out = elu(agg + b2), dtype per flags[0]
    transpose_w<<<DIM, DIM, 0, stream>>>(W2, Wt, flags);
    gemm_mfma<<<gemm_blocks, 256, 0, stream>>>((const u16*)d_out, Wt, xw, N_NODES);
    aggregate<<<N_NODES / 4, 256, 0, stream>>>(xw, rowptr, colidx, dis, b2, d_out, flags, 1);
}

// Round 3
// 1302.494 us; speedup vs baseline: 1.2761x; 1.2761x over previous
//
#include <hip/hip_runtime.h>
#include <math.h>

#define N_NODES 100000
#define N_EDGES 3200000
#define DIM 256
#define SCAN_B 1024
#define SCAN_NBLK ((N_NODES + SCAN_B - 1) / SCAN_B)  // 98

typedef unsigned short u16;
typedef unsigned int u32;
typedef __attribute__((ext_vector_type(8))) short bf16x8;
typedef __attribute__((ext_vector_type(4))) float f32x4;

__device__ __forceinline__ float bf2f(u16 u) {
    union { u32 i; float f; } v; v.i = ((u32)u) << 16; return v.f;
}
__device__ __forceinline__ u16 f2bf(float f) {
    union { float f; u32 i; } v; v.f = f;
    u32 x = v.i;
    return (u16)((x + 0x7fffu + ((x >> 16) & 1u)) >> 16);
}
__device__ __forceinline__ float sane(float v) {
    union { float f; u32 i; } u; u.f = v;
    if ((u.i & 0x7f800000u) == 0x7f800000u) return 0.f;
    return v;
}
__device__ __forceinline__ int iclamp(int v, int lo, int hi) {
    return v < lo ? lo : (v > hi ? hi : v);
}

// ---- runtime format probes (64-lane parallel) ---------------------------
// flags[0]: 1 => float tensors are fp32, 0 => bf16
// flags[1]: 1 => edge_index is int64 (lo/hi word pairs), 0 => int32
__global__ void detect_kernel(const u32* __restrict__ xw_words,
                              const int* __restrict__ ei, int* __restrict__ flags) {
    int lane = threadIdx.x;
    int cnt = 0;
#pragma unroll
    for (int j = 0; j < 4; ++j) {
        u32 e = (xw_words[lane + 64 * j] >> 7) & 0xffu;
        cnt += (e >= 0x70 && e <= 0x88) ? 1 : 0;
    }
    int nz = 0;
#pragma unroll
    for (int j = 0; j < 4; ++j) nz += (ei[2 * (lane + 64 * j) + 1] != 0) ? 1 : 0;
#pragma unroll
    for (int off = 32; off; off >>= 1) {
        cnt += __shfl_down(cnt, off, 64);
        nz += __shfl_down(nz, off, 64);
    }
    if (lane == 0) {
        flags[0] = (cnt < 128) ? 1 : 0;
        flags[1] = (nz == 0) ? 1 : 0;
    }
}

__device__ __forceinline__ int edge_val(const int* __restrict__ ei, int which,
                                        int i, int f64) {
    long long idx = (long long)which * N_EDGES + i;
    int v = f64 ? ei[idx * 2] : ei[idx];
    return iclamp(v, 0, N_NODES - 1);
}

// ---- canonicalize x to internal bf16 -----------------------------------
__global__ void convert_x(const void* __restrict__ xin, u16* __restrict__ xbf,
                          const int* __restrict__ flags) {
    long long i = (long long)blockIdx.x * blockDim.x + threadIdx.x;
    if (i >= (long long)N_NODES * DIM) return;
    float v = flags[0] ? ((const float*)xin)[i] : bf2f(((const u16*)xin)[i]);
    xbf[i] = f2bf(sane(v));
}

// ---- CSR build ---------------------------------------------------------
__global__ void count_deg(const int* __restrict__ ei, int* __restrict__ rowcount,
                          const int* __restrict__ flags) {
    int i = blockIdx.x * blockDim.x + threadIdx.x;
    if (i < N_EDGES) {
        int d = edge_val(ei, 1, i, flags[1]);
        atomicAdd(&rowcount[d], 1);
    }
}

__global__ void compute_dis(const int* __restrict__ rowcount, float* __restrict__ dis) {
    int i = blockIdx.x * blockDim.x + threadIdx.x;
    if (i < N_NODES) {
        int c = iclamp(rowcount[i], 0, N_EDGES);
        dis[i] = rsqrtf((float)(c + 1));  // +1 self loop
    }
}

// ---- parallel 3-phase exclusive scan ------------------------------------
__global__ __launch_bounds__(SCAN_B) void scan_block_sums(const int* __restrict__ cnt,
                                                          int* __restrict__ bsum) {
    __shared__ int ws[16];
    int i = blockIdx.x * SCAN_B + threadIdx.x;
    int v = (i < N_NODES) ? cnt[i] : 0;
#pragma unroll
    for (int off = 32; off; off >>= 1) v += __shfl_down(v, off, 64);
    if ((threadIdx.x & 63) == 0) ws[threadIdx.x >> 6] = v;
    __syncthreads();
    if (threadIdx.x < 16) {
        int t = ws[threadIdx.x];
#pragma unroll
        for (int off = 8; off; off >>= 1) t += __shfl_down(t, off, 16);
        if (threadIdx.x == 0) bsum[blockIdx.x] = t;
    }
}

__global__ void scan_bsum(int* __restrict__ bsum, int* __restrict__ rowptr) {
    __shared__ int sdata[128];
    int i = threadIdx.x;  // 128 threads
    int v = (i < SCAN_NBLK) ? bsum[i] : 0;
    sdata[i] = v;
    __syncthreads();
    for (int off = 1; off < 128; off <<= 1) {
        int t = (i >= off) ? sdata[i - off] : 0;
        __syncthreads();
        sdata[i] += t;
        __syncthreads();
    }
    if (i < SCAN_NBLK) bsum[i] = sdata[i] - v;  // exclusive
    if (i == 0) rowptr[N_NODES] = sdata[127];   // total = E
}

__global__ __launch_bounds__(SCAN_B) void scan_final(const int* __restrict__ cnt,
                                                     const int* __restrict__ bsum,
                                                     int* __restrict__ rowptr,
                                                     int* __restrict__ cursor) {
    __shared__ int ws[16];
    int lane = threadIdx.x & 63;
    int wid = threadIdx.x >> 6;
    int i = blockIdx.x * SCAN_B + threadIdx.x;
    int c = (i < N_NODES) ? cnt[i] : 0;
    int v = c;
#pragma unroll
    for (int off = 1; off < 64; off <<= 1) {
        int t = __shfl_up(v, off, 64);
        if (lane >= off) v += t;
    }
    if (lane == 63) ws[wid] = v;
    __syncthreads();
    int woff = 0;
    for (int w = 0; w < wid; ++w) woff += ws[w];
    int excl = bsum[blockIdx.x] + woff + v - c;
    if (i < N_NODES) { rowptr[i] = excl; cursor[i] = excl; }
}

__global__ void fill_csr(const int* __restrict__ ei, int* __restrict__ cursor,
                         int* __restrict__ colidx, const int* __restrict__ flags) {
    int i = blockIdx.x * blockDim.x + threadIdx.x;
    if (i < N_EDGES) {
        int f = flags[1];
        int s = edge_val(ei, 0, i, f);
        int d = edge_val(ei, 1, i, f);
        int pos = atomicAdd(&cursor[d], 1);
        colidx[pos] = s;
    }
}

// ---- weight transpose (dtype-aware) ------------------------------------
__global__ void transpose_w(const void* __restrict__ W, u16* __restrict__ Wt,
                            const int* __restrict__ flags) {
    int n = blockIdx.x;
    int k = threadIdx.x;
    float v = flags[0] ? ((const float*)W)[k * DIM + n]
                       : bf2f(((const u16*)W)[k * DIM + n]);
    Wt[n * DIM + k] = f2bf(sane(v));
}

// ---- dense GEMM: xw = A @ W via Wt, bf16 MFMA --------------------------
__global__ __launch_bounds__(256) void gemm_mfma(const u16* __restrict__ A,
                                                 const u16* __restrict__ Wt,
                                                 u16* __restrict__ out, int M) {
    int wid = threadIdx.x >> 6;
    int lane = threadIdx.x & 63;
    int rt = blockIdx.x * 4 + wid;
    if (rt * 16 >= M) return;
    int m = lane & 15;
    int quad = lane >> 4;
    const u16* arow = A + (size_t)(rt * 16 + m) * DIM + quad * 8;

    f32x4 acc[16];
#pragma unroll
    for (int t = 0; t < 16; ++t) acc[t] = (f32x4){0.f, 0.f, 0.f, 0.f};

#pragma unroll
    for (int ks = 0; ks < 8; ++ks) {
        bf16x8 a = *(const bf16x8*)(arow + ks * 32);
#pragma unroll
        for (int t = 0; t < 16; ++t) {
            bf16x8 b = *(const bf16x8*)(Wt + (size_t)(t * 16 + m) * DIM + ks * 32 + quad * 8);
            acc[t] = __builtin_amdgcn_mfma_f32_16x16x32_bf16(a, b, acc[t], 0, 0, 0);
        }
    }
#pragma unroll
    for (int t = 0; t < 16; ++t) {
#pragma unroll
        for (int r = 0; r < 4; ++r) {
            int row = rt * 16 + quad * 4 + r;
            int c = t * 16 + m;
            out[(size_t)row * DIM + c] = f2bf(sane(acc[t][r]));
        }
    }
}

// ---- aggregation + bias + ELU (8-way MLP unroll) ------------------------
__global__ __launch_bounds__(256) void aggregate(const u16* __restrict__ xw,
                                                 const int* __restrict__ rowptr,
                                                 const int* __restrict__ colidx,
                                                 const float* __restrict__ dis,
                                                 const void* __restrict__ bias,
                                                 void* __restrict__ out,
                                                 const int* __restrict__ flags,
                                                 int final_layer) {
    int wid = threadIdx.x >> 6;
    int lane = threadIdx.x & 63;
    int node = blockIdx.x * 4 + wid;
    if (node >= N_NODES) return;
    int c0 = lane * 4;
    const u16* base = xw + c0;

    float dn = dis[node];
    float a0, a1, a2, a3;
    {
        ushort4 v = *(const ushort4*)(base + (size_t)node * DIM);
        a0 = dn * bf2f(v.x); a1 = dn * bf2f(v.y);
        a2 = dn * bf2f(v.z); a3 = dn * bf2f(v.w);
    }
    int beg = rowptr[node];
    int end = rowptr[node + 1];
    int e = beg;
    for (; e + 8 <= end; e += 8) {
        int s[8];
        float w[8];
        ushort4 vv[8];
#pragma unroll
        for (int k = 0; k < 8; ++k) s[k] = colidx[e + k];
#pragma unroll
        for (int k = 0; k < 8; ++k) vv[k] = *(const ushort4*)(base + (size_t)s[k] * DIM);
#pragma unroll
        for (int k = 0; k < 8; ++k) w[k] = dis[s[k]];
#pragma unroll
        for (int k = 0; k < 8; ++k) {
            a0 += w[k] * bf2f(vv[k].x);
            a1 += w[k] * bf2f(vv[k].y);
            a2 += w[k] * bf2f(vv[k].z);
            a3 += w[k] * bf2f(vv[k].w);
        }
    }
    for (; e < end; ++e) {
        int s = colidx[e];
        float w = dis[s];
        ushort4 v = *(const ushort4*)(base + (size_t)s * DIM);
        a0 += w * bf2f(v.x); a1 += w * bf2f(v.y);
        a2 += w * bf2f(v.z); a3 += w * bf2f(v.w);
    }

    float b0, b1, b2, b3;
    int f32mode = flags[0];
    if (f32mode) {
        float4 bv = *(const float4*)((const float*)bias + c0);
        b0 = bv.x; b1 = bv.y; b2 = bv.z; b3 = bv.w;
    } else {
        ushort4 bv = *(const ushort4*)((const u16*)bias + c0);
        b0 = bf2f(bv.x); b1 = bf2f(bv.y); b2 = bf2f(bv.z); b3 = bf2f(bv.w);
    }
    float o0 = dn * a0 + b0;
    float o1 = dn * a1 + b1;
    float o2 = dn * a2 + b2;
    float o3 = dn * a3 + b3;
    o0 = sane(o0 > 0.f ? o0 : expm1f(o0));
    o1 = sane(o1 > 0.f ? o1 : expm1f(o1));
    o2 = sane(o2 > 0.f ? o2 : expm1f(o2));
    o3 = sane(o3 > 0.f ? o3 : expm1f(o3));
    if (final_layer && f32mode) {
        float4 ov; ov.x = o0; ov.y = o1; ov.z = o2; ov.w = o3;
        *(float4*)((float*)out + (size_t)node * DIM + c0) = ov;
    } else {
        ushort4 ov;
        ov.x = f2bf(o0); ov.y = f2bf(o1); ov.z = f2bf(o2); ov.w = f2bf(o3);
        *(ushort4*)((u16*)out + (size_t)node * DIM + c0) = ov;
    }
}

// ---- launch ------------------------------------------------------------
extern "C" void kernel_launch(void* const* d_in, const int* in_sizes, int n_in,
                              void* d_out, int out_size, void* d_ws, size_t ws_size,
                              hipStream_t stream) {
    const void* x  = d_in[0];
    const int*  ei = (const int*)d_in[1];
    const void* W1 = d_in[2];
    const void* b1 = d_in[3];
    const void* W2 = d_in[4];
    const void* b2 = d_in[5];

    char* ws = (char*)d_ws;
    size_t off = 0;
    auto alloc = [&](size_t bytes) {
        void* p = ws + off;
        off = (off + bytes + 255) & ~(size_t)255;
        return p;
    };
    int*   flags    = (int*)alloc(256);
    int*   rowcount = (int*)alloc((size_t)N_NODES * 4);
    int*   rowptr   = (int*)alloc((size_t)(N_NODES + 1) * 4);
    int*   cursor   = (int*)alloc((size_t)N_NODES * 4);
    int*   colidx   = (int*)alloc((size_t)N_EDGES * 4);
    float* dis      = (float*)alloc((size_t)N_NODES * 4);
    int*   bsum     = (int*)alloc((size_t)SCAN_NBLK * 4 + 256);
    u16*   Wt       = (u16*)alloc((size_t)DIM * DIM * 2);
    u16*   xw       = (u16*)alloc((size_t)N_NODES * DIM * 2);
    (void)ws_size;

    u16* xbf = (u16*)d_out;  // d_out doubles as bf16-x scratch, then h

    detect_kernel<<<1, 64, 0, stream>>>((const u32*)x, ei, flags);
    hipMemsetAsync(rowcount, 0, (size_t)N_NODES * 4, stream);
    convert_x<<<(N_NODES * DIM + 255) / 256, 256, 0, stream>>>(x, xbf, flags);
    count_deg<<<(N_EDGES + 255) / 256, 256, 0, stream>>>(ei, rowcount, flags);
    compute_dis<<<(N_NODES + 255) / 256, 256, 0, stream>>>(rowcount, dis);
    scan_block_sums<<<SCAN_NBLK, SCAN_B, 0, stream>>>(rowcount, bsum);
    scan_bsum<<<1, 128, 0, stream>>>(bsum, rowptr);
    scan_final<<<SCAN_NBLK, SCAN_B, 0, stream>>>(rowcount, bsum, rowptr, cursor);
    fill_csr<<<(N_EDGES + 255) / 256, 256, 0, stream>>>(ei, cursor, colidx, flags);

    int gemm_blocks = (N_NODES / 16 + 3) / 4;

    // layer 1
    transpose_w<<<DIM, DIM, 0, stream>>>(W1, Wt, flags);
    gemm_mfma<<<gemm_blocks, 256, 0, stream>>>(xbf, Wt, xw, N_NODES);
    aggregate<<<N_NODES / 4, 256, 0, stream>>>(xw, rowptr, colidx, dis, b1, d_out, flags, 0);

    // layer 2
    transpose_w<<<DIM, DIM, 0, stream>>>(W2, Wt, flags);
    gemm_mfma<<<gemm_blocks, 256, 0, stream>>>((const u16*)d_out, Wt, xw, N_NODES);
    aggregate<<<N_NODES / 4, 256, 0, stream>>>(xw, rowptr, colidx, dis, b2, d_out, flags, 1);
}

// Round 4
// 1236.181 us; speedup vs baseline: 1.3446x; 1.0536x over previous
//
#include <hip/hip_runtime.h>
#include <math.h>

#define N_NODES 100000
#define N_EDGES 3200000
#define DIM 256
#define SCAN_B 1024
#define SCAN_NBLK ((N_NODES + SCAN_B - 1) / SCAN_B)  // 98
#define NPASS 8
#define WIN ((N_NODES + NPASS - 1) / NPASS)  // 12500

typedef unsigned short u16;
typedef unsigned int u32;
typedef __attribute__((ext_vector_type(8))) short bf16x8;
typedef __attribute__((ext_vector_type(4))) float f32x4;

__device__ __forceinline__ float bf2f(u16 u) {
    union { u32 i; float f; } v; v.i = ((u32)u) << 16; return v.f;
}
__device__ __forceinline__ u16 f2bf(float f) {
    union { float f; u32 i; } v; v.f = f;
    u32 x = v.i;
    return (u16)((x + 0x7fffu + ((x >> 16) & 1u)) >> 16);
}
__device__ __forceinline__ float sane(float v) {
    union { float f; u32 i; } u; u.f = v;
    if ((u.i & 0x7f800000u) == 0x7f800000u) return 0.f;
    return v;
}
__device__ __forceinline__ int iclamp(int v, int lo, int hi) {
    return v < lo ? lo : (v > hi ? hi : v);
}

// ---- runtime format probes ----------------------------------------------
// flags[0]: 1 => float tensors are fp32, 0 => bf16
// flags[1]: 1 => edge_index is int64 (lo/hi word pairs), 0 => int32
__global__ void detect_kernel(const u32* __restrict__ xw_words,
                              const int* __restrict__ ei, int* __restrict__ flags) {
    int lane = threadIdx.x;
    int cnt = 0;
#pragma unroll
    for (int j = 0; j < 4; ++j) {
        u32 e = (xw_words[lane + 64 * j] >> 7) & 0xffu;
        cnt += (e >= 0x70 && e <= 0x88) ? 1 : 0;
    }
    int nz = 0;
#pragma unroll
    for (int j = 0; j < 4; ++j) nz += (ei[2 * (lane + 64 * j) + 1] != 0) ? 1 : 0;
#pragma unroll
    for (int off = 32; off; off >>= 1) {
        cnt += __shfl_down(cnt, off, 64);
        nz += __shfl_down(nz, off, 64);
    }
    if (lane == 0) {
        flags[0] = (cnt < 128) ? 1 : 0;
        flags[1] = (nz == 0) ? 1 : 0;
    }
}

__device__ __forceinline__ int edge_val(const int* __restrict__ ei, int which,
                                        int i, int f64) {
    long long idx = (long long)which * N_EDGES + i;
    int v = f64 ? ei[idx * 2] : ei[idx];
    return iclamp(v, 0, N_NODES - 1);
}

// ---- canonicalize x to internal bf16 ------------------------------------
__global__ void convert_x(const void* __restrict__ xin, u16* __restrict__ xbf,
                          const int* __restrict__ flags) {
    long long i = (long long)blockIdx.x * blockDim.x + threadIdx.x;
    if (i >= (long long)N_NODES * DIM) return;
    float v = flags[0] ? ((const float*)xin)[i] : bf2f(((const u16*)xin)[i]);
    xbf[i] = f2bf(sane(v));
}

// ---- CSR build: count + int32 conversion fused --------------------------
__global__ void count_convert(const int* __restrict__ ei, int* __restrict__ rowcount,
                              int* __restrict__ src32, int* __restrict__ dst32,
                              const int* __restrict__ flags) {
    int i = blockIdx.x * blockDim.x + threadIdx.x;
    if (i < N_EDGES) {
        int f = flags[1];
        int s = edge_val(ei, 0, i, f);
        int d = edge_val(ei, 1, i, f);
        src32[i] = s;
        dst32[i] = d;
        atomicAdd(&rowcount[d], 1);
    }
}

__global__ void compute_dis(const int* __restrict__ rowcount, float* __restrict__ dis) {
    int i = blockIdx.x * blockDim.x + threadIdx.x;
    if (i < N_NODES) {
        int c = iclamp(rowcount[i], 0, N_EDGES);
        dis[i] = rsqrtf((float)(c + 1));  // +1 self loop
    }
}

// ---- parallel 3-phase exclusive scan ------------------------------------
__global__ __launch_bounds__(SCAN_B) void scan_block_sums(const int* __restrict__ cnt,
                                                          int* __restrict__ bsum) {
    __shared__ int ws[16];
    int i = blockIdx.x * SCAN_B + threadIdx.x;
    int v = (i < N_NODES) ? cnt[i] : 0;
#pragma unroll
    for (int off = 32; off; off >>= 1) v += __shfl_down(v, off, 64);
    if ((threadIdx.x & 63) == 0) ws[threadIdx.x >> 6] = v;
    __syncthreads();
    if (threadIdx.x < 16) {
        int t = ws[threadIdx.x];
#pragma unroll
        for (int off = 8; off; off >>= 1) t += __shfl_down(t, off, 16);
        if (threadIdx.x == 0) bsum[blockIdx.x] = t;
    }
}

__global__ void scan_bsum(int* __restrict__ bsum, int* __restrict__ rowptr) {
    __shared__ int sdata[128];
    int i = threadIdx.x;  // 128 threads
    int v = (i < SCAN_NBLK) ? bsum[i] : 0;
    sdata[i] = v;
    __syncthreads();
    for (int off = 1; off < 128; off <<= 1) {
        int t = (i >= off) ? sdata[i - off] : 0;
        __syncthreads();
        sdata[i] += t;
        __syncthreads();
    }
    if (i < SCAN_NBLK) bsum[i] = sdata[i] - v;  // exclusive
    if (i == 0) rowptr[N_NODES] = sdata[127];   // total = E
}

__global__ __launch_bounds__(SCAN_B) void scan_final(const int* __restrict__ cnt,
                                                     const int* __restrict__ bsum,
                                                     int* __restrict__ rowptr,
                                                     int* __restrict__ cursor) {
    __shared__ int ws[16];
    int lane = threadIdx.x & 63;
    int wid = threadIdx.x >> 6;
    int i = blockIdx.x * SCAN_B + threadIdx.x;
    int c = (i < N_NODES) ? cnt[i] : 0;
    int v = c;
#pragma unroll
    for (int off = 1; off < 64; off <<= 1) {
        int t = __shfl_up(v, off, 64);
        if (lane >= off) v += t;
    }
    if (lane == 63) ws[wid] = v;
    __syncthreads();
    int woff = 0;
    for (int w = 0; w < wid; ++w) woff += ws[w];
    int excl = bsum[blockIdx.x] + woff + v - c;
    if (i < N_NODES) { rowptr[i] = excl; cursor[i] = excl; }
}

// ---- windowed CSR fill: pass p handles dst in [lo, lo+WIN) --------------
// scatter window ~1.6 MB -> L2-resident, kills the 16x write amplification
__global__ void fill_csr_pass(const int* __restrict__ src32,
                              const int* __restrict__ dst32,
                              int* __restrict__ cursor, int* __restrict__ colidx,
                              int lo) {
    int i = blockIdx.x * blockDim.x + threadIdx.x;
    if (i < N_EDGES) {
        int d = dst32[i];
        if ((unsigned)(d - lo) < (unsigned)WIN) {
            int pos = atomicAdd(&cursor[d], 1);
            colidx[pos] = src32[i];
        }
    }
}

// ---- weight transpose (dtype-aware) -------------------------------------
__global__ void transpose_w(const void* __restrict__ W, u16* __restrict__ Wt,
                            const int* __restrict__ flags) {
    int n = blockIdx.x;
    int k = threadIdx.x;
    float v = flags[0] ? ((const float*)W)[k * DIM + n]
                       : bf2f(((const u16*)W)[k * DIM + n]);
    Wt[n * DIM + k] = f2bf(sane(v));
}

// ---- dense GEMM: register-resident B ------------------------------------
// block = one 16-row tile (6250 blocks); wave w holds B-frags for cols
// [w*64, w*64+64) in 128 VGPRs; per wave: 8 A-frag loads + 32 MFMAs.
__global__ __launch_bounds__(256) void gemm_mfma(const u16* __restrict__ A,
                                                 const u16* __restrict__ Wt,
                                                 u16* __restrict__ out) {
    int w = threadIdx.x >> 6;   // col-group 0..3
    int lane = threadIdx.x & 63;
    int rt = blockIdx.x;        // row tile (100000/16 = 6250 exact)
    int m = lane & 15;
    int quad = lane >> 4;

    bf16x8 B[4][8];
#pragma unroll
    for (int t2 = 0; t2 < 4; ++t2)
#pragma unroll
        for (int ks = 0; ks < 8; ++ks)
            B[t2][ks] = *(const bf16x8*)(Wt + (size_t)((w * 4 + t2) * 16 + m) * DIM +
                                         ks * 32 + quad * 8);

    const u16* arow = A + (size_t)(rt * 16 + m) * DIM + quad * 8;
    f32x4 acc[4];
#pragma unroll
    for (int t2 = 0; t2 < 4; ++t2) acc[t2] = (f32x4){0.f, 0.f, 0.f, 0.f};

#pragma unroll
    for (int ks = 0; ks < 8; ++ks) {
        bf16x8 a = *(const bf16x8*)(arow + ks * 32);
#pragma unroll
        for (int t2 = 0; t2 < 4; ++t2)
            acc[t2] = __builtin_amdgcn_mfma_f32_16x16x32_bf16(a, B[t2][ks], acc[t2], 0, 0, 0);
    }

#pragma unroll
    for (int t2 = 0; t2 < 4; ++t2) {
#pragma unroll
        for (int r = 0; r < 4; ++r) {
            int row = rt * 16 + quad * 4 + r;
            int c = w * 64 + t2 * 16 + m;
            out[(size_t)row * DIM + c] = f2bf(sane(acc[t2][r]));
        }
    }
}

// ---- aggregation + bias + ELU (8-way MLP unroll) ------------------------
__global__ __launch_bounds__(256) void aggregate(const u16* __restrict__ xw,
                                                 const int* __restrict__ rowptr,
                                                 const int* __restrict__ colidx,
                                                 const float* __restrict__ dis,
                                                 const void* __restrict__ bias,
                                                 void* __restrict__ out,
                                                 const int* __restrict__ flags,
                                                 int final_layer) {
    int wid = threadIdx.x >> 6;
    int lane = threadIdx.x & 63;
    int node = blockIdx.x * 4 + wid;
    if (node >= N_NODES) return;
    int c0 = lane * 4;
    const u16* base = xw + c0;

    float dn = dis[node];
    float a0, a1, a2, a3;
    {
        ushort4 v = *(const ushort4*)(base + (size_t)node * DIM);
        a0 = dn * bf2f(v.x); a1 = dn * bf2f(v.y);
        a2 = dn * bf2f(v.z); a3 = dn * bf2f(v.w);
    }
    int beg = rowptr[node];
    int end = rowptr[node + 1];
    int e = beg;
    for (; e + 8 <= end; e += 8) {
        int s[8];
        float w[8];
        ushort4 vv[8];
#pragma unroll
        for (int k = 0; k < 8; ++k) s[k] = colidx[e + k];
#pragma unroll
        for (int k = 0; k < 8; ++k) vv[k] = *(const ushort4*)(base + (size_t)s[k] * DIM);
#pragma unroll
        for (int k = 0; k < 8; ++k) w[k] = dis[s[k]];
#pragma unroll
        for (int k = 0; k < 8; ++k) {
            a0 += w[k] * bf2f(vv[k].x);
            a1 += w[k] * bf2f(vv[k].y);
            a2 += w[k] * bf2f(vv[k].z);
            a3 += w[k] * bf2f(vv[k].w);
        }
    }
    for (; e < end; ++e) {
        int s = colidx[e];
        float w = dis[s];
        ushort4 v = *(const ushort4*)(base + (size_t)s * DIM);
        a0 += w * bf2f(v.x); a1 += w * bf2f(v.y);
        a2 += w * bf2f(v.z); a3 += w * bf2f(v.w);
    }

    float b0, b1, b2, b3;
    int f32mode = flags[0];
    if (f32mode) {
        float4 bv = *(const float4*)((const float*)bias + c0);
        b0 = bv.x; b1 = bv.y; b2 = bv.z; b3 = bv.w;
    } else {
        ushort4 bv = *(const ushort4*)((const u16*)bias + c0);
        b0 = bf2f(bv.x); b1 = bf2f(bv.y); b2 = bf2f(bv.z); b3 = bf2f(bv.w);
    }
    float o0 = dn * a0 + b0;
    float o1 = dn * a1 + b1;
    float o2 = dn * a2 + b2;
    float o3 = dn * a3 + b3;
    o0 = sane(o0 > 0.f ? o0 : expm1f(o0));
    o1 = sane(o1 > 0.f ? o1 : expm1f(o1));
    o2 = sane(o2 > 0.f ? o2 : expm1f(o2));
    o3 = sane(o3 > 0.f ? o3 : expm1f(o3));
    if (final_layer && f32mode) {
        float4 ov; ov.x = o0; ov.y = o1; ov.z = o2; ov.w = o3;
        *(float4*)((float*)out + (size_t)node * DIM + c0) = ov;
    } else {
        ushort4 ov;
        ov.x = f2bf(o0); ov.y = f2bf(o1); ov.z = f2bf(o2); ov.w = f2bf(o3);
        *(ushort4*)((u16*)out + (size_t)node * DIM + c0) = ov;
    }
}

// ---- launch -------------------------------------------------------------
extern "C" void kernel_launch(void* const* d_in, const int* in_sizes, int n_in,
                              void* d_out, int out_size, void* d_ws, size_t ws_size,
                              hipStream_t stream) {
    const void* x  = d_in[0];
    const int*  ei = (const int*)d_in[1];
    const void* W1 = d_in[2];
    const void* b1 = d_in[3];
    const void* W2 = d_in[4];
    const void* b2 = d_in[5];

    char* ws = (char*)d_ws;
    size_t off = 0;
    auto alloc = [&](size_t bytes) {
        void* p = ws + off;
        off = (off + bytes + 255) & ~(size_t)255;
        return p;
    };
    int*   flags    = (int*)alloc(256);
    int*   rowcount = (int*)alloc((size_t)N_NODES * 4);
    int*   rowptr   = (int*)alloc((size_t)(N_NODES + 1) * 4);
    int*   cursor   = (int*)alloc((size_t)N_NODES * 4);
    int*   colidx   = (int*)alloc((size_t)N_EDGES * 4);
    float* dis      = (float*)alloc((size_t)N_NODES * 4);
    int*   bsum     = (int*)alloc((size_t)SCAN_NBLK * 4 + 256);
    u16*   Wt       = (u16*)alloc((size_t)DIM * DIM * 2);
    u16*   xw       = (u16*)alloc((size_t)N_NODES * DIM * 2);
    (void)ws_size;

    // src32/dst32 alias the xw region: their lifetime (count_convert..fill
    // passes) ends before gemm_mfma first writes xw.
    int* src32 = (int*)xw;
    int* dst32 = src32 + N_EDGES;

    u16* xbf = (u16*)d_out;  // d_out doubles as bf16-x scratch, then h

    detect_kernel<<<1, 64, 0, stream>>>((const u32*)x, ei, flags);
    hipMemsetAsync(rowcount, 0, (size_t)N_NODES * 4, stream);
    count_convert<<<(N_EDGES + 255) / 256, 256, 0, stream>>>(ei, rowcount, src32, dst32, flags);
    compute_dis<<<(N_NODES + 255) / 256, 256, 0, stream>>>(rowcount, dis);
    scan_block_sums<<<SCAN_NBLK, SCAN_B, 0, stream>>>(rowcount, bsum);
    scan_bsum<<<1, 128, 0, stream>>>(bsum, rowptr);
    scan_final<<<SCAN_NBLK, SCAN_B, 0, stream>>>(rowcount, bsum, rowptr, cursor);
    for (int p = 0; p < NPASS; ++p)
        fill_csr_pass<<<(N_EDGES + 255) / 256, 256, 0, stream>>>(src32, dst32, cursor,
                                                                 colidx, p * WIN);
    convert_x<<<(N_NODES * DIM + 255) / 256, 256, 0, stream>>>(x, xbf, flags);

    // layer 1
    transpose_w<<<DIM, DIM, 0, stream>>>(W1, Wt, flags);
    gemm_mfma<<<N_NODES / 16, 256, 0, stream>>>(xbf, Wt, xw);
    aggregate<<<N_NODES / 4, 256, 0, stream>>>(xw, rowptr, colidx, dis, b1, d_out, flags, 0);

    // layer 2
    transpose_w<<<DIM, DIM, 0, stream>>>(W2, Wt, flags);
    gemm_mfma<<<N_NODES / 16, 256, 0, stream>>>((const u16*)d_out, Wt, xw);
    aggregate<<<N_NODES / 4, 256, 0, stream>>>(xw, rowptr, colidx, dis, b2, d_out, flags, 1);
}